// Round 8
// baseline (512.407 us; speedup 1.0000x reference)
//
#include <hip/hip_runtime.h>
#include <cstddef>
#include <cstdint>

typedef _Float16 f16x8 __attribute__((ext_vector_type(8)));
typedef _Float16 f16x4 __attribute__((ext_vector_type(4)));
typedef float f32x4 __attribute__((ext_vector_type(4)));

static constexpr int BATCH = 8;
static constexpr int TQ = 2048;
static constexpr int TK = 2048;
static constexpr int DIM = 1024;
static constexpr size_t CTX_ELEMS = (size_t)BATCH * TQ * DIM;   // 16,777,216
static constexpr size_t ATT_ELEMS = (size_t)BATCH * TQ * TK;    // 33,554,432

// ws layout (halves): dec16 | enc16 | encT16 | W16
static constexpr size_t WS_DEC = 0;
static constexpr size_t WS_ENC = WS_DEC + CTX_ELEMS;
static constexpr size_t WS_ENCT = WS_ENC + CTX_ELEMS;
static constexpr size_t WS_W = WS_ENCT + CTX_ELEMS;
static constexpr size_t WS_NEEDED_BYTES = (WS_W + ATT_ELEMS) * 2;  // 167.8 MB

__device__ __forceinline__ void async16(const void* g, const void* l) {
  __builtin_amdgcn_global_load_lds(
      (const __attribute__((address_space(1))) unsigned int*)g,
      (__attribute__((address_space(3))) unsigned int*)l, 16, 0, 0);
}

__device__ __forceinline__ f16x8 cvt8(float4 a, float4 b) {
  f16x8 h;
  h[0] = (_Float16)a.x; h[1] = (_Float16)a.y; h[2] = (_Float16)a.z; h[3] = (_Float16)a.w;
  h[4] = (_Float16)b.x; h[5] = (_Float16)b.y; h[6] = (_Float16)b.z; h[7] = (_Float16)b.w;
  return h;
}

// ===========================================================================
// FAST PATH (needs 168 MB ws)
// ===========================================================================

// enc fp32 [b][k][d] -> enc16 [b][k][d] AND encT16 [b][d][k];
// PLUS (merged) dec fp32 -> dec16 elementwise.
__global__ __launch_bounds__(256) void convert_kernel(
    const float* __restrict__ enc, const float* __restrict__ dec,
    _Float16* __restrict__ enc16, _Float16* __restrict__ encT,
    _Float16* __restrict__ dec16) {
  __shared__ _Float16 sT[64 * 72];
  const int k0 = blockIdx.x * 64, d0 = blockIdx.y * 64, b = blockIdx.z;
  const int t = threadIdx.x;
  const int krow = t >> 2;           // 0..63
  const int dcol = (t & 3) * 16;     // 0,16,32,48

  const float* src = enc + ((size_t)b * TK + k0 + krow) * DIM + d0 + dcol;
  float4 f0 = *(const float4*)(src);
  float4 f1 = *(const float4*)(src + 4);
  float4 f2 = *(const float4*)(src + 8);
  float4 f3 = *(const float4*)(src + 12);
  _Float16 h[16];
#pragma unroll
  for (int i = 0; i < 4; i++) {
    h[i]      = (_Float16)((&f0.x)[i]);
    h[i + 4]  = (_Float16)((&f1.x)[i]);
    h[i + 8]  = (_Float16)((&f2.x)[i]);
    h[i + 12] = (_Float16)((&f3.x)[i]);
  }
  _Float16* dsts = enc16 + ((size_t)b * TK + k0 + krow) * DIM + d0 + dcol;
  *(f16x8*)dsts = *(const f16x8*)&h[0];
  *(f16x8*)(dsts + 8) = *(const f16x8*)&h[8];
#pragma unroll
  for (int i = 0; i < 16; i++)
    sT[(dcol + i) * 72 + krow] = h[i];

  // merged dec conversion (independent of the enc/LDS dataflow)
  {
    const int bid = ((blockIdx.z * gridDim.y) + blockIdx.y) * gridDim.x + blockIdx.x;
    size_t base = (size_t)bid * 4096 + (size_t)t * 16;
    float4 a0 = *(const float4*)(dec + base);
    float4 a1 = *(const float4*)(dec + base + 4);
    float4 a2 = *(const float4*)(dec + base + 8);
    float4 a3 = *(const float4*)(dec + base + 12);
    *(f16x8*)(dec16 + base) = cvt8(a0, a1);
    *(f16x8*)(dec16 + base + 8) = cvt8(a2, a3);
  }

  __syncthreads();

  const int drow = t >> 2;
  const int kg = (t & 3) * 16;
  f16x8 v0 = *(const f16x8*)&sT[drow * 72 + kg];
  f16x8 v1 = *(const f16x8*)&sT[drow * 72 + kg + 8];
  _Float16* dst = encT + ((size_t)b * DIM + d0 + drow) * TK + k0 + kg;
  *(f16x8*)dst = v0;
  *(f16x8*)(dst + 8) = v1;
}

// ---------------------------------------------------------------------------
// m97-geometry NT GEMM: 128x128 tile, BK=64, 4 waves (each 64x64, acc[4][4]),
// double-buffered 32 KB LDS, __launch_bounds__(256,4) -> 4 blocks/CU.
// Mechanism: cross-BLOCK overlap — when one block drains at its staging
// barrier, the other 3 resident blocks issue MFMA (m114/m97: this is what
// the 1-block/CU 256^2 kernel could not do; all intra-block schedule
// variants tied at ~650 TF).
// Layout: 32-half rows, chunk-XOR swizzle LDS[row][c] = g[row][c^(row&3)]
// (verified rounds 3/7): coalesced DMA source, linear dest, min-depth reads.
// ---------------------------------------------------------------------------
template <int M, int N, int K>
__global__ __launch_bounds__(256, 4) void gemm97(
    const _Float16* __restrict__ A, const _Float16* __restrict__ B,
    float* __restrict__ C) {
  __shared__ _Float16 sA[2][128 * 32];
  __shared__ _Float16 sB[2][128 * 32];

  const int b = blockIdx.x, nt = blockIdx.y, mt = blockIdx.z;
  const int t = threadIdx.x;
  const int lane = t & 63, w = t >> 6;
  const int tm = lane & 15, quad = lane >> 4;
  const int wm = w >> 1, wn = w & 1;       // 2x2 wave grid; wave tile 64x64

  const _Float16* Ab = A + ((size_t)b * M + mt * 128) * K;
  const _Float16* Bb = B + ((size_t)b * N + nt * 128) * K;

  // staging lane geometry (swizzled source chunk within same 64B row window)
  const int srow = lane >> 2;                    // 0..15
  const int schunk = (lane & 3) ^ (srow & 3);    // XOR swizzle

  // fragment read bases; rows read are = tm (mod 4)
  const int xorc = (quad ^ (tm & 3)) * 8;
  const int aBase = (wm * 64 + tm) * 32 + xorc;
  const int bBase = (wn * 64 + tm) * 32 + xorc;

  f32x4 acc[4][4] = {};

  for (int k0 = 0; k0 < K; k0 += 64) {
    __syncthreads();  // previous iteration's LDS reads done
    // stage both 32-half k-subs: per wave 4 A-rows-groups + 4 B (8 async16)
#pragma unroll
    for (int s = 0; s < 2; s++) {
#pragma unroll
      for (int j = 0; j < 2; j++) {
        const int row0 = 16 * (j * 4 + w);   // rows row0..row0+15
        async16(Ab + (size_t)(row0 + srow) * K + k0 + s * 32 + schunk * 8,
                &sA[s][row0 * 32]);
        async16(Bb + (size_t)(row0 + srow) * K + k0 + s * 32 + schunk * 8,
                &sB[s][row0 * 32]);
      }
    }
    __syncthreads();  // staging drained + all waves arrived

#pragma unroll
    for (int s = 0; s < 2; s++) {
      f16x8 aF[4], bF[4];
#pragma unroll
      for (int i = 0; i < 4; i++)
        aF[i] = *(const f16x8*)&sA[s][aBase + i * 512];
#pragma unroll
      for (int j = 0; j < 4; j++)
        bF[j] = *(const f16x8*)&sB[s][bBase + j * 512];
#pragma unroll
      for (int i = 0; i < 4; i++)
#pragma unroll
        for (int j = 0; j < 4; j++)
          acc[i][j] = __builtin_amdgcn_mfma_f32_16x16x32_f16(
              aF[i], bF[j], acc[i][j], 0, 0, 0);
    }
  }

  // C/D layout: col = tm, row = quad*4 + rr
#pragma unroll
  for (int i = 0; i < 4; i++) {
#pragma unroll
    for (int rr = 0; rr < 4; rr++) {
      size_t row = (size_t)b * M + mt * 128 + wm * 64 + i * 16 + quad * 4 + rr;
      float* Crow = C + row * (size_t)N + nt * 128 + wn * 64 + tm;
#pragma unroll
      for (int j = 0; j < 4; j++) Crow[j * 16] = acc[i][j][rr];
    }
  }
}

// masked softmax in-place over S rows; optionally also emits fp16 copy.
__global__ __launch_bounds__(256) void softmax_kernel(
    float* __restrict__ S, const int* __restrict__ mask, _Float16* __restrict__ W16) {
  const int row = blockIdx.x;
  const int b = row >> 11;
  float* srow = S + (size_t)row * TK;
  const int* mrow = mask + (size_t)b * TK;
  const int t = threadIdx.x;

  float4 s0 = *(const float4*)(srow + t * 8);
  float4 s1 = *(const float4*)(srow + t * 8 + 4);
  int4 m0 = *(const int4*)(mrow + t * 8);
  int4 m1 = *(const int4*)(mrow + t * 8 + 4);

  float v[8] = {s0.x, s0.y, s0.z, s0.w, s1.x, s1.y, s1.z, s1.w};
  const int mm[8] = {m0.x, m0.y, m0.z, m0.w, m1.x, m1.y, m1.z, m1.w};
#pragma unroll
  for (int i = 0; i < 8; i++)
    if (!mm[i]) v[i] += -1e9f;

  float mx = v[0];
#pragma unroll
  for (int i = 1; i < 8; i++) mx = fmaxf(mx, v[i]);
#pragma unroll
  for (int off = 32; off > 0; off >>= 1) mx = fmaxf(mx, __shfl_down(mx, off));

  __shared__ float redm[4];
  __shared__ float reds[4];
  if ((t & 63) == 0) redm[t >> 6] = mx;
  __syncthreads();
  mx = fmaxf(fmaxf(redm[0], redm[1]), fmaxf(redm[2], redm[3]));

  float e[8];
  float lsum = 0.f;
#pragma unroll
  for (int i = 0; i < 8; i++) {
    e[i] = __expf(v[i] - mx);
    lsum += e[i];
  }
#pragma unroll
  for (int off = 32; off > 0; off >>= 1) lsum += __shfl_down(lsum, off);
  if ((t & 63) == 0) reds[t >> 6] = lsum;
  __syncthreads();
  const float inv = 1.0f / (reds[0] + reds[1] + reds[2] + reds[3]);

  float4 o0 = {e[0] * inv, e[1] * inv, e[2] * inv, e[3] * inv};
  float4 o1 = {e[4] * inv, e[5] * inv, e[6] * inv, e[7] * inv};
  *(float4*)(srow + t * 8) = o0;
  *(float4*)(srow + t * 8 + 4) = o1;
  if (W16) {
    f16x8 h;
    h[0] = (_Float16)o0.x; h[1] = (_Float16)o0.y; h[2] = (_Float16)o0.z; h[3] = (_Float16)o0.w;
    h[4] = (_Float16)o1.x; h[5] = (_Float16)o1.y; h[6] = (_Float16)o1.z; h[7] = (_Float16)o1.w;
    *(f16x8*)(W16 + (size_t)row * TK + t * 8) = h;
  }
}

// ===========================================================================
// FALLBACK PATH (used only if ws too small)
// ===========================================================================
static constexpr int BM = 128, BN = 128, BK = 32;
static constexpr int LDSS = 40;

__global__ __launch_bounds__(256) void score_kernel_fb(
    const float* __restrict__ dec, const float* __restrict__ enc,
    float* __restrict__ S) {
  __shared__ _Float16 sA[BM * LDSS];
  __shared__ _Float16 sB[BN * LDSS];
  const int nt = blockIdx.x, mt = blockIdx.y, b = blockIdx.z;
  const int t = threadIdx.x;
  const int lane = t & 63, wave = t >> 6;
  const int wm = wave >> 1, wn = wave & 1;
  const int tm = lane & 15, quad = lane >> 4;
  const float* Abase = dec + ((size_t)b * TQ + mt * BM) * DIM;
  const float* Bbase = enc + ((size_t)b * TK + nt * BN) * DIM;
  f32x4 acc[4][4] = {};
  const int r = t >> 2;
  const int c8 = (t & 3) * 8;
  for (int k0 = 0; k0 < DIM; k0 += BK) {
    float4 a0 = *(const float4*)(Abase + (size_t)r * DIM + k0 + c8);
    float4 a1 = *(const float4*)(Abase + (size_t)r * DIM + k0 + c8 + 4);
    float4 a2 = *(const float4*)(Abase + (size_t)(r + 64) * DIM + k0 + c8);
    float4 a3 = *(const float4*)(Abase + (size_t)(r + 64) * DIM + k0 + c8 + 4);
    float4 b0 = *(const float4*)(Bbase + (size_t)r * DIM + k0 + c8);
    float4 b1 = *(const float4*)(Bbase + (size_t)r * DIM + k0 + c8 + 4);
    float4 b2 = *(const float4*)(Bbase + (size_t)(r + 64) * DIM + k0 + c8);
    float4 b3 = *(const float4*)(Bbase + (size_t)(r + 64) * DIM + k0 + c8 + 4);
    __syncthreads();
    *(f16x8*)&sA[r * LDSS + c8] = cvt8(a0, a1);
    *(f16x8*)&sA[(r + 64) * LDSS + c8] = cvt8(a2, a3);
    *(f16x8*)&sB[r * LDSS + c8] = cvt8(b0, b1);
    *(f16x8*)&sB[(r + 64) * LDSS + c8] = cvt8(b2, b3);
    __syncthreads();
    f16x8 aF[4], bF[4];
#pragma unroll
    for (int i = 0; i < 4; i++)
      aF[i] = *(const f16x8*)&sA[(wm * 64 + i * 16 + tm) * LDSS + quad * 8];
#pragma unroll
    for (int j = 0; j < 4; j++)
      bF[j] = *(const f16x8*)&sB[(wn * 64 + j * 16 + tm) * LDSS + quad * 8];
#pragma unroll
    for (int i = 0; i < 4; i++)
#pragma unroll
      for (int j = 0; j < 4; j++)
        acc[i][j] = __builtin_amdgcn_mfma_f32_16x16x32_f16(aF[i], bF[j], acc[i][j], 0, 0, 0);
  }
#pragma unroll
  for (int i = 0; i < 4; i++) {
#pragma unroll
    for (int rr = 0; rr < 4; rr++) {
      size_t rowoff = ((size_t)b * TQ + mt * BM + wm * 64 + i * 16 + quad * 4 + rr) * (size_t)TK;
#pragma unroll
      for (int j = 0; j < 4; j++)
        S[rowoff + nt * BN + wn * 64 + j * 16 + tm] = acc[i][j][rr];
    }
  }
}

__global__ __launch_bounds__(256) void ctx_kernel_fb(
    const float* __restrict__ W, const float* __restrict__ enc,
    float* __restrict__ C) {
  __shared__ _Float16 sA[BM * LDSS];
  __shared__ _Float16 sB[BN * LDSS];
  const int nt = blockIdx.x;
  const int mt = blockIdx.y;
  const int b = blockIdx.z;
  const int t = threadIdx.x;
  const int lane = t & 63, wave = t >> 6;
  const int wm = wave >> 1, wn = wave & 1;
  const int tm = lane & 15, quad = lane >> 4;
  const float* Abase = W + ((size_t)b * TQ + mt * BM) * TK;
  const float* Ebase = enc + (size_t)b * TK * DIM + nt * BN;
  f32x4 acc[4][4] = {};
  const int r = t >> 2;
  const int c8 = (t & 3) * 8;
  const int kkB = (t & 7) * 4;
  const int nnB = (t >> 3) * 4;
  for (int k0 = 0; k0 < TK; k0 += BK) {
    float4 a0 = *(const float4*)(Abase + (size_t)r * TK + k0 + c8);
    float4 a1 = *(const float4*)(Abase + (size_t)r * TK + k0 + c8 + 4);
    float4 a2 = *(const float4*)(Abase + (size_t)(r + 64) * TK + k0 + c8);
    float4 a3 = *(const float4*)(Abase + (size_t)(r + 64) * TK + k0 + c8 + 4);
    float4 f[4];
#pragma unroll
    for (int i = 0; i < 4; i++)
      f[i] = *(const float4*)(Ebase + (size_t)(k0 + kkB + i) * DIM + nnB);
    __syncthreads();
    *(f16x8*)&sA[r * LDSS + c8] = cvt8(a0, a1);
    *(f16x8*)&sA[(r + 64) * LDSS + c8] = cvt8(a2, a3);
#pragma unroll
    for (int c = 0; c < 4; c++) {
      f16x4 h;
      h[0] = (_Float16)((&f[0].x)[c]);
      h[1] = (_Float16)((&f[1].x)[c]);
      h[2] = (_Float16)((&f[2].x)[c]);
      h[3] = (_Float16)((&f[3].x)[c]);
      *(f16x4*)&sB[(nnB + c) * LDSS + kkB] = h;
    }
    __syncthreads();
    f16x8 aF[4], bF[4];
#pragma unroll
    for (int i = 0; i < 4; i++)
      aF[i] = *(const f16x8*)&sA[(wm * 64 + i * 16 + tm) * LDSS + quad * 8];
#pragma unroll
    for (int j = 0; j < 4; j++)
      bF[j] = *(const f16x8*)&sB[(wn * 64 + j * 16 + tm) * LDSS + quad * 8];
#pragma unroll
    for (int i = 0; i < 4; i++)
#pragma unroll
      for (int j = 0; j < 4; j++)
        acc[i][j] = __builtin_amdgcn_mfma_f32_16x16x32_f16(aF[i], bF[j], acc[i][j], 0, 0, 0);
  }
#pragma unroll
  for (int i = 0; i < 4; i++) {
#pragma unroll
    for (int rr = 0; rr < 4; rr++) {
      size_t rowoff = ((size_t)b * TQ + mt * BM + wm * 64 + i * 16 + quad * 4 + rr) * (size_t)DIM;
#pragma unroll
      for (int j = 0; j < 4; j++)
        C[rowoff + nt * BN + wn * 64 + j * 16 + tm] = acc[i][j][rr];
    }
  }
}

// ===========================================================================
extern "C" void kernel_launch(void* const* d_in, const int* in_sizes, int n_in,
                              void* d_out, int out_size, void* d_ws, size_t ws_size,
                              hipStream_t stream) {
  const float* dec = (const float*)d_in[0];
  const float* enc = (const float*)d_in[1];
  const int* mask = (const int*)d_in[2];

  float* ctx = (float*)d_out;               // [8, 2048, 1024]
  float* attn = (float*)d_out + CTX_ELEMS;  // [8, 2048, 2048]

  dim3 block(256);

  if (ws_size >= WS_NEEDED_BYTES) {
    _Float16* dec16 = (_Float16*)d_ws + WS_DEC;
    _Float16* enc16 = (_Float16*)d_ws + WS_ENC;
    _Float16* encT = (_Float16*)d_ws + WS_ENCT;
    _Float16* W16 = (_Float16*)d_ws + WS_W;

    convert_kernel<<<dim3(TK / 64, DIM / 64, BATCH), block, 0, stream>>>(
        enc, dec, enc16, encT, dec16);
    // grid: (b, nt, mt) — batch fastest for XCD-local L2 sharing
    gemm97<TQ, TK, DIM><<<dim3(BATCH, TK / 128, TQ / 128), block, 0, stream>>>(dec16, enc16, attn);
    softmax_kernel<<<dim3(BATCH * TQ), block, 0, stream>>>(attn, mask, W16);
    gemm97<TQ, DIM, TK><<<dim3(BATCH, DIM / 128, TQ / 128), block, 0, stream>>>(W16, encT, ctx);
  } else {
    score_kernel_fb<<<dim3(TK / BN, TQ / BM, BATCH), block, 0, stream>>>(dec, enc, attn);
    softmax_kernel<<<dim3(BATCH * TQ), block, 0, stream>>>(attn, mask, nullptr);
    ctx_kernel_fb<<<dim3(DIM / BN, TQ / BM, BATCH), block, 0, stream>>>(attn, enc, ctx);
  }
}

// Round 10
// 489.110 us; speedup vs baseline: 1.0476x; 1.0476x over previous
//
#include <hip/hip_runtime.h>
#include <cstddef>
#include <cstdint>

typedef _Float16 f16x8 __attribute__((ext_vector_type(8)));
typedef _Float16 f16x4 __attribute__((ext_vector_type(4)));
typedef float f32x4 __attribute__((ext_vector_type(4)));

static constexpr int BATCH = 8;
static constexpr int TQ = 2048;
static constexpr int TK = 2048;
static constexpr int DIM = 1024;
static constexpr size_t CTX_ELEMS = (size_t)BATCH * TQ * DIM;   // 16,777,216
static constexpr size_t ATT_ELEMS = (size_t)BATCH * TQ * TK;    // 33,554,432

// ws layout (halves): dec16 | enc16 | encT16 | W16
static constexpr size_t WS_DEC = 0;
static constexpr size_t WS_ENC = WS_DEC + CTX_ELEMS;
static constexpr size_t WS_ENCT = WS_ENC + CTX_ELEMS;
static constexpr size_t WS_W = WS_ENCT + CTX_ELEMS;
static constexpr size_t WS_NEEDED_BYTES = (WS_W + ATT_ELEMS) * 2;  // 167.8 MB

__device__ __forceinline__ void async16(const void* g, const void* l) {
  __builtin_amdgcn_global_load_lds(
      (const __attribute__((address_space(1))) unsigned int*)g,
      (__attribute__((address_space(3))) unsigned int*)l, 16, 0, 0);
}

__device__ __forceinline__ f16x8 cvt8(float4 a, float4 b) {
  f16x8 h;
  h[0] = (_Float16)a.x; h[1] = (_Float16)a.y; h[2] = (_Float16)a.z; h[3] = (_Float16)a.w;
  h[4] = (_Float16)b.x; h[5] = (_Float16)b.y; h[6] = (_Float16)b.z; h[7] = (_Float16)b.w;
  return h;
}

// ===========================================================================
// FAST PATH (needs 168 MB ws)
// ===========================================================================

// enc fp32 [b][k][d] -> enc16 [b][k][d] AND encT16 [b][d][k];
// PLUS (merged) dec fp32 -> dec16 elementwise.
__global__ __launch_bounds__(256) void convert_kernel(
    const float* __restrict__ enc, const float* __restrict__ dec,
    _Float16* __restrict__ enc16, _Float16* __restrict__ encT,
    _Float16* __restrict__ dec16) {
  __shared__ _Float16 sT[64 * 72];
  const int k0 = blockIdx.x * 64, d0 = blockIdx.y * 64, b = blockIdx.z;
  const int t = threadIdx.x;
  const int krow = t >> 2;           // 0..63
  const int dcol = (t & 3) * 16;     // 0,16,32,48

  const float* src = enc + ((size_t)b * TK + k0 + krow) * DIM + d0 + dcol;
  float4 f0 = *(const float4*)(src);
  float4 f1 = *(const float4*)(src + 4);
  float4 f2 = *(const float4*)(src + 8);
  float4 f3 = *(const float4*)(src + 12);
  _Float16 h[16];
#pragma unroll
  for (int i = 0; i < 4; i++) {
    h[i]      = (_Float16)((&f0.x)[i]);
    h[i + 4]  = (_Float16)((&f1.x)[i]);
    h[i + 8]  = (_Float16)((&f2.x)[i]);
    h[i + 12] = (_Float16)((&f3.x)[i]);
  }
  _Float16* dsts = enc16 + ((size_t)b * TK + k0 + krow) * DIM + d0 + dcol;
  *(f16x8*)dsts = *(const f16x8*)&h[0];
  *(f16x8*)(dsts + 8) = *(const f16x8*)&h[8];
#pragma unroll
  for (int i = 0; i < 16; i++)
    sT[(dcol + i) * 72 + krow] = h[i];

  // merged dec conversion (independent of the enc/LDS dataflow)
  {
    const int bid = ((blockIdx.z * gridDim.y) + blockIdx.y) * gridDim.x + blockIdx.x;
    size_t base = (size_t)bid * 4096 + (size_t)t * 16;
    float4 a0 = *(const float4*)(dec + base);
    float4 a1 = *(const float4*)(dec + base + 4);
    float4 a2 = *(const float4*)(dec + base + 8);
    float4 a3 = *(const float4*)(dec + base + 12);
    *(f16x8*)(dec16 + base) = cvt8(a0, a1);
    *(f16x8*)(dec16 + base + 8) = cvt8(a2, a3);
  }

  __syncthreads();

  const int drow = t >> 2;
  const int kg = (t & 3) * 16;
  f16x8 v0 = *(const f16x8*)&sT[drow * 72 + kg];
  f16x8 v1 = *(const f16x8*)&sT[drow * 72 + kg + 8];
  _Float16* dst = encT + ((size_t)b * DIM + d0 + drow) * TK + k0 + kg;
  *(f16x8*)dst = v0;
  *(f16x8*)(dst + 8) = v1;
}

// ---------------------------------------------------------------------------
// Conflict-free 256x256 NT GEMM, BK=64, 512 threads (8 waves, 2x4), 128 KB.
// Half-tiles [128 rows][64 halves] (rows = 128 B = full 32-bank span) with
// slot-XOR swizzle: LDS[r][slot] = global[r][slot ^ (r&7)] (slot = 16 B).
//  - ds_read_b128 fragment reads: each 16-lane quarter spreads over all 32
//    banks 2-deep -> conflict-free (G4's verified +89% pattern).
//  - global_load_lds: dest linear (8 rows/instr), source permuted within
//    each row's 128 B window -> 8x128B segments, fully coalesced.
// Schedule: 4 quadrant-phases per K-step {reads; barrier; setprio+16 MFMA;
// barrier}; t+1's 4 half-tiles staged at P1 into opposite parity; single
// vmcnt(0) at P4 (~3 phases issue-to-drain). No intra-iter LDS hazards.
// ---------------------------------------------------------------------------
static constexpr int HT = 8192;  // halves per half-tile (16 KB)

template <int KD>
__device__ __forceinline__ void stage_ht(const _Float16* __restrict__ Xb,
                                         _Float16* ht, int khalf, int w, int lane) {
#pragma unroll
  for (int j = 0; j < 2; ++j) {
    const int r = w * 16 + j * 8 + (lane >> 3);     // row 0..127
    const int slot = (lane & 7) ^ (r & 7);          // inverse swizzle on source
    async16(Xb + (size_t)r * KD + khalf + slot * 8, ht + (w * 16 + j * 8) * 64);
  }
}

template <int M, int N, int K>
__global__ __launch_bounds__(512, 2) void gemm_cf(
    const _Float16* __restrict__ A, const _Float16* __restrict__ B,
    float* __restrict__ C) {
  __shared__ _Float16 lds[65536];  // 8 half-tile slots: [parity][A0 A1 B0 B1]
  constexpr int T = K / 64;

  const int b = blockIdx.x, nt = blockIdx.y, mt = blockIdx.z;
  const int tid = threadIdx.x;
  const int lane = tid & 63, w = tid >> 6;
  const int tm = lane & 15, quad = lane >> 4;
  const int wr = w >> 2, wc = w & 3;   // 2x4 wave grid; wave tile 128x64

  const _Float16* Ab = A + ((size_t)b * M + mt * 256) * K;
  const _Float16* Bb = B + ((size_t)b * N + nt * 256) * K;
  const _Float16* src[4] = {Ab, Ab + (size_t)128 * K, Bb, Bb + (size_t)128 * K};

  const int aht = wr;               // this wave's A half-tile (0/1)
  const int bht = 2 + (wc >> 1);    // this wave's B half-tile (2/3)
  const int brow = (wc & 1) * 64;   // row offset inside B half-tile

  // swizzled read offsets (halves): wanted slot s=0 -> quad, s=1 -> quad+4
  const int s0 = (quad ^ (tm & 7)) * 8;
  const int s1 = s0 ^ 32;           // (quad|4)^(tm&7) == s0^4 slots

  f32x4 acc[8][4] = {};

  // prologue: stage K-step 0 into parity 0 (8 loads/wave)
#pragma unroll
  for (int q = 0; q < 4; ++q)
    stage_ht<K>(src[q], lds + q * HT, 0, w, lane);
  asm volatile("s_waitcnt vmcnt(0)" ::: "memory");
  __builtin_amdgcn_s_barrier();

  for (int t = 0; t < T; ++t) {
    const int p = t & 1, np = p ^ 1;
    const _Float16* hA = lds + (p * 4 + aht) * HT;
    const _Float16* hB = lds + (p * 4 + bht) * HT;
    f16x8 aF[4], bF[4];

    // ---- P1: k-sub 0, row-quadrant 0 (+ stage t+1, opposite parity)
#pragma unroll
    for (int j = 0; j < 4; ++j)
      bF[j] = *(const f16x8*)(hB + (brow + j * 16 + tm) * 64 + s0);
#pragma unroll
    for (int i = 0; i < 4; ++i)
      aF[i] = *(const f16x8*)(hA + (i * 16 + tm) * 64 + s0);
    if (t + 1 < T) {
      const int kh = (t + 1) * 64;
#pragma unroll
      for (int q = 0; q < 4; ++q)
        stage_ht<K>(src[q], lds + (np * 4 + q) * HT, kh, w, lane);
    }
    __builtin_amdgcn_s_barrier();
    __builtin_amdgcn_s_setprio(1);
#pragma unroll
    for (int i = 0; i < 4; ++i)
#pragma unroll
      for (int j = 0; j < 4; ++j)
        acc[i][j] = __builtin_amdgcn_mfma_f32_16x16x32_f16(aF[i], bF[j], acc[i][j], 0, 0, 0);
    __builtin_amdgcn_s_setprio(0);
    __builtin_amdgcn_s_barrier();

    // ---- P2: k-sub 0, row-quadrant 1 (reuse bF)
#pragma unroll
    for (int i = 0; i < 4; ++i)
      aF[i] = *(const f16x8*)(hA + (64 + i * 16 + tm) * 64 + s0);
    __builtin_amdgcn_s_barrier();
    __builtin_amdgcn_s_setprio(1);
#pragma unroll
    for (int i = 0; i < 4; ++i)
#pragma unroll
      for (int j = 0; j < 4; ++j)
        acc[4 + i][j] = __builtin_amdgcn_mfma_f32_16x16x32_f16(aF[i], bF[j], acc[4 + i][j], 0, 0, 0);
    __builtin_amdgcn_s_setprio(0);
    __builtin_amdgcn_s_barrier();

    // ---- P3: k-sub 1, row-quadrant 0
#pragma unroll
    for (int j = 0; j < 4; ++j)
      bF[j] = *(const f16x8*)(hB + (brow + j * 16 + tm) * 64 + s1);
#pragma unroll
    for (int i = 0; i < 4; ++i)
      aF[i] = *(const f16x8*)(hA + (i * 16 + tm) * 64 + s1);
    __builtin_amdgcn_s_barrier();
    __builtin_amdgcn_s_setprio(1);
#pragma unroll
    for (int i = 0; i < 4; ++i)
#pragma unroll
      for (int j = 0; j < 4; ++j)
        acc[i][j] = __builtin_amdgcn_mfma_f32_16x16x32_f16(aF[i], bF[j], acc[i][j], 0, 0, 0);
    __builtin_amdgcn_s_setprio(0);
    __builtin_amdgcn_s_barrier();

    // ---- P4: k-sub 1, row-quadrant 1 (reuse bF) + drain t+1 staging
#pragma unroll
    for (int i = 0; i < 4; ++i)
      aF[i] = *(const f16x8*)(hA + (64 + i * 16 + tm) * 64 + s1);
    __builtin_amdgcn_s_barrier();
    __builtin_amdgcn_s_setprio(1);
#pragma unroll
    for (int i = 0; i < 4; ++i)
#pragma unroll
      for (int j = 0; j < 4; ++j)
        acc[4 + i][j] = __builtin_amdgcn_mfma_f32_16x16x32_f16(aF[i], bF[j], acc[4 + i][j], 0, 0, 0);
    __builtin_amdgcn_s_setprio(0);
    asm volatile("s_waitcnt vmcnt(0)" ::: "memory");
    __builtin_amdgcn_s_barrier();
  }

  // C/D layout: col = tm, row = quad*4 + rr; acc[ih*4+i] covers rows ih*64+i*16
#pragma unroll
  for (int i = 0; i < 8; ++i) {
#pragma unroll
    for (int rr = 0; rr < 4; ++rr) {
      size_t row = (size_t)b * M + mt * 256 + wr * 128 + i * 16 + quad * 4 + rr;
      float* Crow = C + row * (size_t)N + nt * 256 + wc * 64 + tm;
#pragma unroll
      for (int j = 0; j < 4; ++j) Crow[j * 16] = acc[i][j][rr];
    }
  }
}

// masked softmax in-place over S rows; optionally also emits fp16 copy.
__global__ __launch_bounds__(256) void softmax_kernel(
    float* __restrict__ S, const int* __restrict__ mask, _Float16* __restrict__ W16) {
  const int row = blockIdx.x;
  const int b = row >> 11;
  float* srow = S + (size_t)row * TK;
  const int* mrow = mask + (size_t)b * TK;
  const int t = threadIdx.x;

  float4 s0 = *(const float4*)(srow + t * 8);
  float4 s1 = *(const float4*)(srow + t * 8 + 4);
  int4 m0 = *(const int4*)(mrow + t * 8);
  int4 m1 = *(const int4*)(mrow + t * 8 + 4);

  float v[8] = {s0.x, s0.y, s0.z, s0.w, s1.x, s1.y, s1.z, s1.w};
  const int mm[8] = {m0.x, m0.y, m0.z, m0.w, m1.x, m1.y, m1.z, m1.w};
#pragma unroll
  for (int i = 0; i < 8; i++)
    if (!mm[i]) v[i] += -1e9f;

  float mx = v[0];
#pragma unroll
  for (int i = 1; i < 8; i++) mx = fmaxf(mx, v[i]);
#pragma unroll
  for (int off = 32; off > 0; off >>= 1) mx = fmaxf(mx, __shfl_down(mx, off));

  __shared__ float redm[4];
  __shared__ float reds[4];
  if ((t & 63) == 0) redm[t >> 6] = mx;
  __syncthreads();
  mx = fmaxf(fmaxf(redm[0], redm[1]), fmaxf(redm[2], redm[3]));

  float e[8];
  float lsum = 0.f;
#pragma unroll
  for (int i = 0; i < 8; i++) {
    e[i] = __expf(v[i] - mx);
    lsum += e[i];
  }
#pragma unroll
  for (int off = 32; off > 0; off >>= 1) lsum += __shfl_down(lsum, off);
  if ((t & 63) == 0) reds[t >> 6] = lsum;
  __syncthreads();
  const float inv = 1.0f / (reds[0] + reds[1] + reds[2] + reds[3]);

  float4 o0 = {e[0] * inv, e[1] * inv, e[2] * inv, e[3] * inv};
  float4 o1 = {e[4] * inv, e[5] * inv, e[6] * inv, e[7] * inv};
  *(float4*)(srow + t * 8) = o0;
  *(float4*)(srow + t * 8 + 4) = o1;
  if (W16) {
    f16x8 h;
    h[0] = (_Float16)o0.x; h[1] = (_Float16)o0.y; h[2] = (_Float16)o0.z; h[3] = (_Float16)o0.w;
    h[4] = (_Float16)o1.x; h[5] = (_Float16)o1.y; h[6] = (_Float16)o1.z; h[7] = (_Float16)o1.w;
    *(f16x8*)(W16 + (size_t)row * TK + t * 8) = h;
  }
}

// ===========================================================================
// FALLBACK PATH (used only if ws too small)
// ===========================================================================
static constexpr int BM = 128, BN = 128, BK = 32;
static constexpr int LDSS = 40;

__global__ __launch_bounds__(256) void score_kernel_fb(
    const float* __restrict__ dec, const float* __restrict__ enc,
    float* __restrict__ S) {
  __shared__ _Float16 sA[BM * LDSS];
  __shared__ _Float16 sB[BN * LDSS];
  const int nt = blockIdx.x, mt = blockIdx.y, b = blockIdx.z;
  const int t = threadIdx.x;
  const int lane = t & 63, wave = t >> 6;
  const int wm = wave >> 1, wn = wave & 1;
  const int tm = lane & 15, quad = lane >> 4;
  const float* Abase = dec + ((size_t)b * TQ + mt * BM) * DIM;
  const float* Bbase = enc + ((size_t)b * TK + nt * BN) * DIM;
  f32x4 acc[4][4] = {};
  const int r = t >> 2;
  const int c8 = (t & 3) * 8;
  for (int k0 = 0; k0 < DIM; k0 += BK) {
    float4 a0 = *(const float4*)(Abase + (size_t)r * DIM + k0 + c8);
    float4 a1 = *(const float4*)(Abase + (size_t)r * DIM + k0 + c8 + 4);
    float4 a2 = *(const float4*)(Abase + (size_t)(r + 64) * DIM + k0 + c8);
    float4 a3 = *(const float4*)(Abase + (size_t)(r + 64) * DIM + k0 + c8 + 4);
    float4 b0 = *(const float4*)(Bbase + (size_t)r * DIM + k0 + c8);
    float4 b1 = *(const float4*)(Bbase + (size_t)r * DIM + k0 + c8 + 4);
    float4 b2 = *(const float4*)(Bbase + (size_t)(r + 64) * DIM + k0 + c8);
    float4 b3 = *(const float4*)(Bbase + (size_t)(r + 64) * DIM + k0 + c8 + 4);
    __syncthreads();
    *(f16x8*)&sA[r * LDSS + c8] = cvt8(a0, a1);
    *(f16x8*)&sA[(r + 64) * LDSS + c8] = cvt8(a2, a3);
    *(f16x8*)&sB[r * LDSS + c8] = cvt8(b0, b1);
    *(f16x8*)&sB[(r + 64) * LDSS + c8] = cvt8(b2, b3);
    __syncthreads();
    f16x8 aF[4], bF[4];
#pragma unroll
    for (int i = 0; i < 4; i++)
      aF[i] = *(const f16x8*)&sA[(wm * 64 + i * 16 + tm) * LDSS + quad * 8];
#pragma unroll
    for (int j = 0; j < 4; j++)
      bF[j] = *(const f16x8*)&sB[(wn * 64 + j * 16 + tm) * LDSS + quad * 8];
#pragma unroll
    for (int i = 0; i < 4; i++)
#pragma unroll
      for (int j = 0; j < 4; j++)
        acc[i][j] = __builtin_amdgcn_mfma_f32_16x16x32_f16(aF[i], bF[j], acc[i][j], 0, 0, 0);
  }
#pragma unroll
  for (int i = 0; i < 4; i++) {
#pragma unroll
    for (int rr = 0; rr < 4; rr++) {
      size_t rowoff = ((size_t)b * TQ + mt * BM + wm * 64 + i * 16 + quad * 4 + rr) * (size_t)TK;
#pragma unroll
      for (int j = 0; j < 4; j++)
        S[rowoff + nt * BN + wn * 64 + j * 16 + tm] = acc[i][j][rr];
    }
  }
}

__global__ __launch_bounds__(256) void ctx_kernel_fb(
    const float* __restrict__ W, const float* __restrict__ enc,
    float* __restrict__ C) {
  __shared__ _Float16 sA[BM * LDSS];
  __shared__ _Float16 sB[BN * LDSS];
  const int nt = blockIdx.x;
  const int mt = blockIdx.y;
  const int b = blockIdx.z;
  const int t = threadIdx.x;
  const int lane = t & 63, wave = t >> 6;
  const int wm = wave >> 1, wn = wave & 1;
  const int tm = lane & 15, quad = lane >> 4;
  const float* Abase = W + ((size_t)b * TQ + mt * BM) * TK;
  const float* Ebase = enc + (size_t)b * TK * DIM + nt * BN;
  f32x4 acc[4][4] = {};
  const int r = t >> 2;
  const int c8 = (t & 3) * 8;
  const int kkB = (t & 7) * 4;
  const int nnB = (t >> 3) * 4;
  for (int k0 = 0; k0 < TK; k0 += BK) {
    float4 a0 = *(const float4*)(Abase + (size_t)r * TK + k0 + c8);
    float4 a1 = *(const float4*)(Abase + (size_t)r * TK + k0 + c8 + 4);
    float4 a2 = *(const float4*)(Abase + (size_t)(r + 64) * TK + k0 + c8);
    float4 a3 = *(const float4*)(Abase + (size_t)(r + 64) * TK + k0 + c8 + 4);
    float4 f[4];
#pragma unroll
    for (int i = 0; i < 4; i++)
      f[i] = *(const float4*)(Ebase + (size_t)(k0 + kkB + i) * DIM + nnB);
    __syncthreads();
    *(f16x8*)&sA[r * LDSS + c8] = cvt8(a0, a1);
    *(f16x8*)&sA[(r + 64) * LDSS + c8] = cvt8(a2, a3);
#pragma unroll
    for (int c = 0; c < 4; c++) {
      f16x4 h;
      h[0] = (_Float16)((&f[0].x)[c]);
      h[1] = (_Float16)((&f[1].x)[c]);
      h[2] = (_Float16)((&f[2].x)[c]);
      h[3] = (_Float16)((&f[3].x)[c]);
      *(f16x4*)&sB[(nnB + c) * LDSS + kkB] = h;
    }
    __syncthreads();
    f16x8 aF[4], bF[4];
#pragma unroll
    for (int i = 0; i < 4; i++)
      aF[i] = *(const f16x8*)&sA[(wm * 64 + i * 16 + tm) * LDSS + quad * 8];
#pragma unroll
    for (int j = 0; j < 4; j++)
      bF[j] = *(const f16x8*)&sB[(wn * 64 + j * 16 + tm) * LDSS + quad * 8];
#pragma unroll
    for (int i = 0; i < 4; i++)
#pragma unroll
      for (int j = 0; j < 4; j++)
        acc[i][j] = __builtin_amdgcn_mfma_f32_16x16x32_f16(aF[i], bF[j], acc[i][j], 0, 0, 0);
  }
#pragma unroll
  for (int i = 0; i < 4; i++) {
#pragma unroll
    for (int rr = 0; rr < 4; rr++) {
      size_t rowoff = ((size_t)b * TQ + mt * BM + wm * 64 + i * 16 + quad * 4 + rr) * (size_t)DIM;
#pragma unroll
      for (int j = 0; j < 4; j++)
        C[rowoff + nt * BN + wn * 64 + j * 16 + tm] = acc[i][j][rr];
    }
  }
}

// ===========================================================================
extern "C" void kernel_launch(void* const* d_in, const int* in_sizes, int n_in,
                              void* d_out, int out_size, void* d_ws, size_t ws_size,
                              hipStream_t stream) {
  const float* dec = (const float*)d_in[0];
  const float* enc = (const float*)d_in[1];
  const int* mask = (const int*)d_in[2];

  float* ctx = (float*)d_out;               // [8, 2048, 1024]
  float* attn = (float*)d_out + CTX_ELEMS;  // [8, 2048, 2048]

  dim3 block(256);

  if (ws_size >= WS_NEEDED_BYTES) {
    _Float16* dec16 = (_Float16*)d_ws + WS_DEC;
    _Float16* enc16 = (_Float16*)d_ws + WS_ENC;
    _Float16* encT = (_Float16*)d_ws + WS_ENCT;
    _Float16* W16 = (_Float16*)d_ws + WS_W;

    convert_kernel<<<dim3(TK / 64, DIM / 64, BATCH), block, 0, stream>>>(
        enc, dec, enc16, encT, dec16);
    // grid: (b, nt, mt) — batch fastest for XCD-local L2 sharing
    gemm_cf<TQ, TK, DIM><<<dim3(BATCH, TK / 256, TQ / 256), dim3(512), 0, stream>>>(dec16, enc16, attn);
    softmax_kernel<<<dim3(BATCH * TQ), block, 0, stream>>>(attn, mask, W16);
    gemm_cf<TQ, DIM, TK><<<dim3(BATCH, DIM / 256, TQ / 256), dim3(512), 0, stream>>>(W16, encT, ctx);
  } else {
    score_kernel_fb<<<dim3(TK / BN, TQ / BM, BATCH), block, 0, stream>>>(dec, enc, attn);
    softmax_kernel<<<dim3(BATCH * TQ), block, 0, stream>>>(attn, mask, nullptr);
    ctx_kernel_fb<<<dim3(DIM / BN, TQ / BM, BATCH), block, 0, stream>>>(attn, enc, ctx);
  }
}